// Round 1
// 1407.093 us; speedup vs baseline: 1.0092x; 1.0092x over previous
//
#include <hip/hip_runtime.h>
#include <hip/hip_bf16.h>

#define TOK 1024          // B*S
#define H 1024
#define NK 4
#define NV 32000
#define NN 128000         // NK*NV
#define EPSR 1e-5f
#define EPSL 1e-10f

typedef __attribute__((ext_vector_type(8))) short short8;
typedef __attribute__((ext_vector_type(4))) float float4v;

// ---------------- RMSNorm: x -> xf (f32) + xb (bf16, 16B-chunk swizzled) ----------------
// xb chunk swizzle: within each 64B window (4x16B chunks), logical chunk c is stored at
// physical slot c ^ ((token>>1)&3). The GEMM stages xb linearly via global_load_lds and
// applies the matching XOR on the LDS frag read -> A-side bank conflicts drop 8-way -> 2-way.
__global__ __launch_bounds__(256) void k_rmsnorm(const float* __restrict__ hs,
                                                 const float* __restrict__ scale,
                                                 float* __restrict__ xf,
                                                 __hip_bfloat16* __restrict__ xb) {
    int t = blockIdx.x;
    int tid = threadIdx.x;
    int w = tid >> 6, l = tid & 63;
    float4 v = ((const float4*)(hs + (size_t)t * H))[tid];
    float ss = v.x * v.x + v.y * v.y + v.z * v.z + v.w * v.w;
#pragma unroll
    for (int m = 32; m; m >>= 1) ss += __shfl_xor(ss, m);
    __shared__ float red[4];
    if (l == 0) red[w] = ss;
    __syncthreads();
    float tot = red[0] + red[1] + red[2] + red[3];
    float rs = rsqrtf(tot * (1.0f / (float)H) + EPSR);
    float4 sc = ((const float4*)scale)[tid];
    float4 y;
    y.x = v.x * rs * sc.x; y.y = v.y * rs * sc.y;
    y.z = v.z * rs * sc.z; y.w = v.w * rs * sc.w;
    ((float4*)(xf + (size_t)t * H))[tid] = y;
    union { __hip_bfloat162 h; unsigned int u; } p0, p1;
    p0.h = __float22bfloat162_rn(make_float2(y.x, y.y));
    p1.h = __float22bfloat162_rn(make_float2(y.z, y.w));
    uint2 pk; pk.x = p0.u; pk.y = p1.u;
    int c = tid >> 1, hh = tid & 1;                 // 16B chunk id, 8B half
    int cs = (c & ~3) | ((c & 3) ^ ((t >> 1) & 3)); // swizzled chunk slot
    ((uint2*)(xb + (size_t)t * H))[cs * 2 + hh] = pk;
}

// ---------------- Gate MLP: xf -> gate_weights (TOK x 4, softmaxed) ----------------
__global__ __launch_bounds__(256) void k_gate(const float* __restrict__ xf,
                                              const float* __restrict__ Wgd,
                                              const float* __restrict__ bgd,
                                              const float* __restrict__ Wgu,
                                              const float* __restrict__ bgu,
                                              float* __restrict__ gate_w) {
    __shared__ float xs[8][H];
    __shared__ float gs[8][512];
    int t0 = blockIdx.x * 8;
    int tid = threadIdx.x;
#pragma unroll
    for (int i = 0; i < 8; i++) {
        int idx = i * 256 + tid;
        int r = idx >> 8, c4 = idx & 255;
        *(float4*)&xs[r][c4 * 4] = *(const float4*)&xf[(size_t)(t0 + r) * H + c4 * 4];
    }
    __syncthreads();
    float acc[8][2];
#pragma unroll
    for (int r = 0; r < 8; r++) { acc[r][0] = 0.f; acc[r][1] = 0.f; }
    int d0 = tid, d1 = tid + 256;
    for (int h = 0; h < H; h += 4) {
        float w0[4], w1[4];
#pragma unroll
        for (int j = 0; j < 4; j++) {
            w0[j] = Wgd[(size_t)(h + j) * 512 + d0];
            w1[j] = Wgd[(size_t)(h + j) * 512 + d1];
        }
#pragma unroll
        for (int r = 0; r < 8; r++) {
            float4 xv = *(const float4*)&xs[r][h];
            acc[r][0] += xv.x * w0[0] + xv.y * w0[1] + xv.z * w0[2] + xv.w * w0[3];
            acc[r][1] += xv.x * w1[0] + xv.y * w1[1] + xv.z * w1[2] + xv.w * w1[3];
        }
    }
    float b0 = bgd[d0], b1 = bgd[d1];
#pragma unroll
    for (int r = 0; r < 8; r++) {
        float v0 = acc[r][0] + b0;
        float v1 = acc[r][1] + b1;
        gs[r][d0] = v0 / (1.f + __expf(-v0));
        gs[r][d1] = v1 / (1.f + __expf(-v1));
    }
    __syncthreads();
    int w = tid >> 6, l = tid & 63;
#pragma unroll
    for (int rr = 0; rr < 2; rr++) {
        int r = w * 2 + rr;
        float4 a = make_float4(0.f, 0.f, 0.f, 0.f);
#pragma unroll
        for (int i = 0; i < 8; i++) {
            int d = i * 64 + l;
            float g = gs[r][d];
            float4 wu = *(const float4*)&Wgu[(size_t)d * 4];
            a.x += g * wu.x; a.y += g * wu.y; a.z += g * wu.z; a.w += g * wu.w;
        }
#pragma unroll
        for (int m = 32; m; m >>= 1) {
            a.x += __shfl_xor(a.x, m);
            a.y += __shfl_xor(a.y, m);
            a.z += __shfl_xor(a.z, m);
            a.w += __shfl_xor(a.w, m);
        }
        if (l == 0) {
            float l0 = a.x + bgu[0], l1 = a.y + bgu[1];
            float l2 = a.z + bgu[2], l3 = a.w + bgu[3];
            float mx = fmaxf(fmaxf(l0, l1), fmaxf(l2, l3));
            float e0 = __expf(l0 - mx), e1 = __expf(l1 - mx);
            float e2 = __expf(l2 - mx), e3 = __expf(l3 - mx);
            float s = e0 + e1 + e2 + e3;
            float inv = 1.f / s;
            float4 o = make_float4(e0 * inv, e1 * inv, e2 * inv, e3 * inv);
            *(float4*)&gate_w[(size_t)(t0 + r) * 4] = o;
        }
    }
}

// ---------------- Fused GEMM: fp32 W converted in-flight, 256x128 tile ----------------
// Replaces k_convw + k_gemm2. Grid = 1000 n-tiles x 4 m-tiles = 4000 blocks.
// 4 waves, each owns a 128x64 quadrant: acc[8][4] (128 VGPR), 32 MFMA per barrier-pair.
// A staged via global_load_lds from pre-swizzled xb; B reg-staged from fp32 W with
// cvt + XOR-swizzled ds_write (proven Path-B code).
__global__ __launch_bounds__(256, 2) void k_gemmF(const __hip_bfloat16* __restrict__ xb,
                                                  const float* __restrict__ W,
                                                  __hip_bfloat16* __restrict__ E,
                                                  float* __restrict__ Z) {
    __shared__ __align__(16) __hip_bfloat16 As[256 * 32];  // [row][k], 64B rows, swizzled chunks
    __shared__ __align__(16) __hip_bfloat16 Bs[128 * 32];  // [n][k], 64B rows, swizzled chunks
    int tid = threadIdx.x;
    int tn = blockIdx.x >> 2;   // 0..999 n-tile (128 cols)
    int tm = blockIdx.x & 2;    // placeholder to keep compiler honest (recomputed below)
    tm = blockIdx.x & 3;        // 0..3 m-tile (256 tokens); low bits spread tn-sharers over XCDs
    size_t n0 = (size_t)tn * 128;
    int l = tid & 63, w = tid >> 6;
    int wm = w >> 1, wn = w & 1;   // wave tile: 128 rows x 64 cols

    float4v acc[8][4];
#pragma unroll
    for (int i = 0; i < 8; i++)
#pragma unroll
        for (int j = 0; j < 4; j++) acc[i][j] = (float4v){0.f, 0.f, 0.f, 0.f};

    for (int k0 = 0; k0 < H; k0 += 32) {
        // --- A: 256 rows x 32k bf16 = 16KB, linear global_load_lds (source pre-swizzled) ---
#pragma unroll
        for (int i = 0; i < 4; i++) {
            int ch = i * 256 + tid;
            int row = ch >> 2, kg = ch & 3;
            const __hip_bfloat16* ga = xb + (size_t)(tm * 256 + row) * H + k0 + kg * 8;
            __builtin_amdgcn_global_load_lds(
                (const __attribute__((address_space(1))) void*)ga,
                (__attribute__((address_space(3))) void*)((char*)As + ch * 16), 16, 0, 0);
        }
        // --- B: 128 cols x 32k from fp32 W, cvt->bf16, swizzled ds_write ---
#pragma unroll
        for (int i = 0; i < 2; i++) {
            int ch = tid + i * 256;
            int n = ch & 127, kg = ch >> 7;
            const float* gp = W + (size_t)(k0 + kg * 8) * NN + n0 + n;
            float f[8];
#pragma unroll
            for (int j = 0; j < 8; j++) f[j] = gp[(size_t)j * NN];
            union { __hip_bfloat162 h; unsigned int u; } q0, q1, q2, q3;
            q0.h = __float22bfloat162_rn(make_float2(f[0], f[1]));
            q1.h = __float22bfloat162_rn(make_float2(f[2], f[3]));
            q2.h = __float22bfloat162_rn(make_float2(f[4], f[5]));
            q3.h = __float22bfloat162_rn(make_float2(f[6], f[7]));
            uint4 pk; pk.x = q0.u; pk.y = q1.u; pk.z = q2.u; pk.w = q3.u;
            int sw = kg ^ ((n >> 1) & 3);
            *(uint4*)((char*)Bs + (n << 6) + (sw << 4)) = pk;
        }
        __syncthreads();
        short8 a[8], b[4];
#pragma unroll
        for (int mf = 0; mf < 8; mf++) {
            int row = wm * 128 + mf * 16 + (l & 15);
            int sa = (l >> 4) ^ ((row >> 1) & 3);
            a[mf] = *(const short8*)((const char*)As + (row << 6) + (sa << 4));
        }
#pragma unroll
        for (int nf = 0; nf < 4; nf++) {
            int n = wn * 64 + nf * 16 + (l & 15);
            int sw = (l >> 4) ^ ((n >> 1) & 3);
            b[nf] = *(const short8*)((const char*)Bs + (n << 6) + (sw << 4));
        }
#pragma unroll
        for (int mf = 0; mf < 8; mf++)
#pragma unroll
            for (int nf = 0; nf < 4; nf++)
                acc[mf][nf] = __builtin_amdgcn_mfma_f32_16x16x32_bf16(
                    a[mf], b[nf], acc[mf][nf], 0, 0, 0);
        __syncthreads();
    }

    int kexp = tn / 250;
    int colbase = wn * 64 + (l & 15);
#pragma unroll
    for (int mf = 0; mf < 8; mf++) {
        float zs[4] = {0.f, 0.f, 0.f, 0.f};
#pragma unroll
        for (int nf = 0; nf < 4; nf++) {
#pragma unroll
            for (int r = 0; r < 4; r++) {
                float e = __expf(acc[mf][nf][r]);
                int row = wm * 128 + mf * 16 + ((l >> 4) << 2) + r;
                int token = tm * 256 + row;
                size_t col = n0 + colbase + nf * 16;
                E[(size_t)token * NN + col] = __float2bfloat16(e);
                zs[r] += e;
            }
        }
#pragma unroll
        for (int r = 0; r < 4; r++) {
            float s = zs[r];
            s += __shfl_xor(s, 1);
            s += __shfl_xor(s, 2);
            s += __shfl_xor(s, 4);
            s += __shfl_xor(s, 8);
            if ((l & 15) == 0) {
                int row = wm * 128 + mf * 16 + ((l >> 4) << 2) + r;
                atomicAdd(&Z[(size_t)(tm * 256 + row) * NK + kexp], s);
            }
        }
    }
}

// ---------------- Final: out = log(sum_k g_k * E / Z_k + eps) ----------------
__device__ __forceinline__ float bf_lo(unsigned int u) { return __uint_as_float(u << 16); }
__device__ __forceinline__ float bf_hi(unsigned int u) { return __uint_as_float(u & 0xffff0000u); }

__global__ __launch_bounds__(256) void k_final(const __hip_bfloat16* __restrict__ E,
                                               const float* __restrict__ gw,
                                               const float* __restrict__ Zp,
                                               float* __restrict__ out) {
    int id = blockIdx.x * 256 + threadIdx.x;
    int t = id / 4000;
    int c = id - t * 4000;
    size_t v0 = (size_t)c * 8;
    float4 g = *(const float4*)(gw + (size_t)t * 4);
    float4 z = *(const float4*)(Zp + (size_t)t * 4);
    float c0 = g.x / z.x, c1 = g.y / z.y, c2 = g.z / z.z, c3 = g.w / z.w;
    const __hip_bfloat16* base = E + (size_t)t * NN + v0;
    uint4 e0 = *(const uint4*)(base);
    uint4 e1 = *(const uint4*)(base + NV);
    uint4 e2 = *(const uint4*)(base + 2 * NV);
    uint4 e3 = *(const uint4*)(base + 3 * NV);
    float m[8];
    m[0] = c0 * bf_lo(e0.x) + c1 * bf_lo(e1.x) + c2 * bf_lo(e2.x) + c3 * bf_lo(e3.x);
    m[1] = c0 * bf_hi(e0.x) + c1 * bf_hi(e1.x) + c2 * bf_hi(e2.x) + c3 * bf_hi(e3.x);
    m[2] = c0 * bf_lo(e0.y) + c1 * bf_lo(e1.y) + c2 * bf_lo(e2.y) + c3 * bf_lo(e3.y);
    m[3] = c0 * bf_hi(e0.y) + c1 * bf_hi(e1.y) + c2 * bf_hi(e2.y) + c3 * bf_hi(e3.y);
    m[4] = c0 * bf_lo(e0.z) + c1 * bf_lo(e1.z) + c2 * bf_lo(e2.z) + c3 * bf_lo(e3.z);
    m[5] = c0 * bf_hi(e0.z) + c1 * bf_hi(e1.z) + c2 * bf_hi(e2.z) + c3 * bf_hi(e3.z);
    m[6] = c0 * bf_lo(e0.w) + c1 * bf_lo(e1.w) + c2 * bf_lo(e2.w) + c3 * bf_lo(e3.w);
    m[7] = c0 * bf_hi(e0.w) + c1 * bf_hi(e1.w) + c2 * bf_hi(e2.w) + c3 * bf_hi(e3.w);
    float4 o0, o1;
    o0.x = __logf(m[0] + EPSL); o0.y = __logf(m[1] + EPSL);
    o0.z = __logf(m[2] + EPSL); o0.w = __logf(m[3] + EPSL);
    o1.x = __logf(m[4] + EPSL); o1.y = __logf(m[5] + EPSL);
    o1.z = __logf(m[6] + EPSL); o1.w = __logf(m[7] + EPSL);
    float* op = out + (size_t)t * NV + v0;
    *(float4*)op = o0;
    *(float4*)(op + 4) = o1;
}

extern "C" void kernel_launch(void* const* d_in, const int* in_sizes, int n_in,
                              void* d_out, int out_size, void* d_ws, size_t ws_size,
                              hipStream_t stream) {
    const float* hs  = (const float*)d_in[0];
    const float* rsc = (const float*)d_in[1];
    const float* gdw = (const float*)d_in[2];
    const float* gdb = (const float*)d_in[3];
    const float* guw = (const float*)d_in[4];
    const float* gub = (const float*)d_in[5];
    const float* ew  = (const float*)d_in[6];
    float* out = (float*)d_out;

    char* ws = (char*)d_ws;
    // layout: xf 4MB | xb 2MB | gate_w 16KB | Z 16KB | E 262MB
    float* xf            = (float*)ws;
    __hip_bfloat16* xb   = (__hip_bfloat16*)(ws + 4194304);
    float* gw            = (float*)(ws + 6291456);
    float* Z             = (float*)(ws + 6307840);
    __hip_bfloat16* E    = (__hip_bfloat16*)(ws + 6324224);

    k_rmsnorm<<<TOK, 256, 0, stream>>>(hs, rsc, xf, xb);
    k_gate<<<TOK / 8, 256, 0, stream>>>(xf, gdw, gdb, guw, gub, gw);
    hipMemsetAsync(Z, 0, (size_t)TOK * NK * sizeof(float), stream);
    k_gemmF<<<(NN / 128) * (TOK / 256), 256, 0, stream>>>(xb, ew, E, Z);
    k_final<<<(TOK * (NV / 8)) / 256, 256, 0, stream>>>(E, gw, Z, out);
}